// Round 1
// baseline (392.625 us; speedup 1.0000x reference)
//
#include <hip/hip_runtime.h>

// Problem constants
#define BB 4
#define GN 2048
#define DD 256
#define GG (GN * GN)            // 4194304

// d_out float offsets (reference return order, flattened)
#define OFF_E   0u
#define OFF_INT 2097152u        // B*G*D
#define OFF_SP  18874368u       // + B*G*G
#define OFF_RG  35651584u
#define OFF_GP  52428800u
#define OFF_CP  56623104u
#define OFF_L0  69206016u

// ---------------------------------------------------------------------------
// Kernel 1: embedding gather + the two 256-length dots (s_i, s_j).
// One wave (64 lanes) per (b,g) row; each lane owns one float4 of the row.
// ---------------------------------------------------------------------------
__global__ __launch_bounds__(64) void k_embed(
    const int* __restrict__ gene_ids, const float* __restrict__ emb,
    const float* __restrict__ w, float* __restrict__ e_out,
    float* __restrict__ s_i, float* __restrict__ s_j) {
  const int row  = blockIdx.x;      // 0 .. B*G-1
  const int lane = threadIdx.x;     // 0 .. 63
  const int gid  = gene_ids[row];

  const float4 v  = ((const float4*)(emb + (size_t)gid * DD))[lane];
  ((float4*)(e_out + (size_t)row * DD))[lane] = v;

  const float4 w0 = ((const float4*)w)[lane];          // w_proj[:256]
  const float4 w1 = ((const float4*)(w + DD))[lane];   // w_proj[256:]
  float di = v.x * w0.x + v.y * w0.y + v.z * w0.z + v.w * w0.w;
  float dj = v.x * w1.x + v.y * w1.y + v.z * w1.z + v.w * w1.w;
#pragma unroll
  for (int off = 32; off > 0; off >>= 1) {
    di += __shfl_down(di, off);
    dj += __shfl_down(dj, off);
  }
  if (lane == 0) { s_i[row] = di; s_j[row] = dj; }
}

// ---------------------------------------------------------------------------
// Kernel 2: gate_probs, class_probs (one-hot), packed per-(i,j) code byte,
// and the sigmoid-sum l0_reg. Each thread handles 4 consecutive k's.
// code[k] = gate | (argmax << 4);  class_value = argmax - 1.
// ---------------------------------------------------------------------------
__device__ __forceinline__ int argmax3(float a, float b, float c) {
  int idx = 0; float best = a;
  if (b > best) { best = b; idx = 1; }
  if (c > best) { idx = 2; }
  return idx;
}
__device__ __forceinline__ float sigf(float x) { return 1.0f / (1.0f + __expf(-x)); }

__global__ __launch_bounds__(256) void k_gate(
    const float* __restrict__ gl, const float* __restrict__ cl,
    float* __restrict__ gate_out, float* __restrict__ cp_out,
    unsigned char* __restrict__ code, float* __restrict__ l0) {
  const int t = blockIdx.x * 256 + threadIdx.x;   // 0 .. GG/4-1
  const float4 g = ((const float4*)gl)[t];
  const float4* clp = (const float4*)cl + (size_t)t * 3;
  const float4 c0 = clp[0], c1 = clp[1], c2 = clp[2];

  const int i0 = argmax3(c0.x, c0.y, c0.z);
  const int i1 = argmax3(c0.w, c1.x, c1.y);
  const int i2 = argmax3(c1.z, c1.w, c2.x);
  const int i3 = argmax3(c2.y, c2.z, c2.w);

  const float gx = g.x > 0.0f ? 1.0f : 0.0f;
  const float gy = g.y > 0.0f ? 1.0f : 0.0f;
  const float gz = g.z > 0.0f ? 1.0f : 0.0f;
  const float gw = g.w > 0.0f ? 1.0f : 0.0f;

  ((float4*)gate_out)[t] = make_float4(gx, gy, gz, gw);

  float4* cpo = (float4*)cp_out + (size_t)t * 3;
  cpo[0] = make_float4(i0 == 0, i0 == 1, i0 == 2, i1 == 0);
  cpo[1] = make_float4(i1 == 1, i1 == 2, i2 == 0, i2 == 1);
  cpo[2] = make_float4(i2 == 2, i3 == 0, i3 == 1, i3 == 2);

  ((uchar4*)code)[t] = make_uchar4(
      (unsigned char)((int)gx | (i0 << 4)), (unsigned char)((int)gy | (i1 << 4)),
      (unsigned char)((int)gz | (i2 << 4)), (unsigned char)((int)gw | (i3 << 4)));

  // l0_reg = sum(sigmoid(gate_logits))
  float s = sigf(g.x) + sigf(g.y) + sigf(g.z) + sigf(g.w);
#pragma unroll
  for (int off = 32; off > 0; off >>= 1) s += __shfl_down(s, off);
  __shared__ float part[4];
  if ((threadIdx.x & 63) == 0) part[threadIdx.x >> 6] = s;
  __syncthreads();
  if (threadIdx.x == 0) atomicAdd(l0, part[0] + part[1] + part[2] + part[3]);
}

// ---------------------------------------------------------------------------
// Kernel 3: the three (B,G,G) outputs. Pure write bandwidth.
// Each thread: one (b, i, j4) -> 3 float4 stores.
// ---------------------------------------------------------------------------
__global__ __launch_bounds__(256) void k_bcast(
    const float* __restrict__ s_i, const float* __restrict__ s_j,
    const float* __restrict__ bptr, const unsigned char* __restrict__ code,
    float* __restrict__ inter, float* __restrict__ sparse,
    float* __restrict__ reg) {
  const int t  = blockIdx.x * 256 + threadIdx.x;  // 0 .. B*G*G/4-1
  const int j4 = t & (GN / 4 - 1);                // 0..511
  const int i  = (t >> 9) & (GN - 1);
  const int b  = t >> 20;

  const float  si = s_i[b * GN + i] + bptr[0];
  const float4 sj = ((const float4*)(s_j + b * GN))[j4];
  const uchar4 cd = ((const uchar4*)(code + (size_t)i * GN))[j4];

  const float4 it4 = make_float4(si + sj.x, si + sj.y, si + sj.z, si + sj.w);
  const float4 sp4 = make_float4(it4.x * (float)(cd.x & 15), it4.y * (float)(cd.y & 15),
                                 it4.z * (float)(cd.z & 15), it4.w * (float)(cd.w & 15));
  const float4 rg4 = make_float4(sp4.x * (float)((cd.x >> 4) - 1), sp4.y * (float)((cd.y >> 4) - 1),
                                 sp4.z * (float)((cd.z >> 4) - 1), sp4.w * (float)((cd.w >> 4) - 1));

  ((float4*)inter)[t]  = it4;
  ((float4*)sparse)[t] = sp4;
  ((float4*)reg)[t]    = rg4;
}

extern "C" void kernel_launch(void* const* d_in, const int* in_sizes, int n_in,
                              void* d_out, int out_size, void* d_ws, size_t ws_size,
                              hipStream_t stream) {
  const int*   gene_ids = (const int*)d_in[0];
  const float* emb      = (const float*)d_in[1];
  const float* w        = (const float*)d_in[2];
  const float* bptr     = (const float*)d_in[3];
  const float* gl       = (const float*)d_in[4];
  const float* cl       = (const float*)d_in[5];
  float* out = (float*)d_out;

  float* s_i = (float*)d_ws;                       // B*G floats
  float* s_j = s_i + BB * GN;                      // B*G floats
  unsigned char* code = (unsigned char*)d_ws + 65536;  // GG bytes

  hipMemsetAsync(out + OFF_L0, 0, sizeof(float), stream);  // l0 accumulator

  k_embed<<<BB * GN, 64, 0, stream>>>(gene_ids, emb, w, out + OFF_E, s_i, s_j);
  k_gate<<<GG / 1024, 256, 0, stream>>>(gl, cl, out + OFF_GP, out + OFF_CP,
                                        code, out + OFF_L0);
  k_bcast<<<(BB * GG / 4) / 256, 256, 0, stream>>>(s_i, s_j, bptr, code,
                                                   out + OFF_INT, out + OFF_SP,
                                                   out + OFF_RG);
}